// Round 6
// baseline (159.996 us; speedup 1.0000x reference)
//
#include <hip/hip_runtime.h>
#include <hip/hip_bf16.h>

#define B_   64
#define NW_  256
#define H_   768

#define AB_    (0.1f / 768.0f)   // ALPHA*BETA
#define OMB_   0.9f              // 1 - BETA
#define K1_    0.1f
#define BP_    1.2f
#define AVDL_  50.0f

typedef __bf16 bf16x8 __attribute__((ext_vector_type(8)));
typedef float  f32x4  __attribute__((ext_vector_type(4)));

// Async global->LDS, 16B per lane, no VGPR round-trip. The compiler NEVER
// auto-emits this (learn_hip common-mistake #1); it is the one proven lever
// (+67% A/B) untried in R0-R5. LDS dest is wave-uniform base + lane*16;
// global src is per-lane.
#define GLL16(g, l)                                                        \
    __builtin_amdgcn_global_load_lds(                                      \
        (const __attribute__((address_space(1))) void*)(g),                \
        (__attribute__((address_space(3))) void*)(l), 16, 0, 0)

// ---------------------------------------------------------------------------
// m97-structure GEMM: 128x128 tile, BK=32, double-buffered LDS staged via
// global_load_lds, fused score epilogue.
// R0-R5 post-mortem: gemm pinned at 44-50us across occupancy 9->36%, L2
// traffic 192->576MB, 48->7 barriers, LDS/no-LDS. No pipe >35%; serial pipe
// work sums to ~1/3 of measured time. The invariant every variant shared:
// the staging round-trip global->VGPR->waitcnt->cvt->ds_write, whose
// latency the compiler never pipelined (VGPR_Count 36-112 across rounds -
// lookahead never stayed resident). R6 deletes the round-trip with
// global_load_lds width=16 (m97 structure, verified 874TF@4096 / ~320TF at
// an equivalent 256-block grid -> ~20us on our FLOPs):
//   - f32 staged DIRECTLY to LDS async; no VGPR wait, no cvt on the
//     staging path. cvt f32->bf16 moves to fragment read (VALU 10% idle).
//   - LDS linear [128][32]f32 per matrix (gll requires linear dest).
//     Bank fix per rule #21 (both-sides-or-neither): per-lane global seg
//     pre-swizzle s_global = (lane&7)^(lane>>3) with linear LDS dest, and
//     the read XORs the same (row&7) -> each b128 wave-read spreads across
//     all 32 banks (8cyc = 1KB floor; unswizzled would be 2x).
//   - Double buffer: stage(kc+1) issued BEFORE compute(kc); __syncthreads
//     (vmcnt drain) at iter end = m97's verified schedule.
// Grid 256 = 4 tiles x 64 batches (1 block/CU; R0-R3 proved occupancy is
// not the lever). bid=t*64+b -> XCD=b%8: one batch's tiles share an XCD L2.
// Wave w: 64x64 quadrant (qm=w>>1, qn=w&1), acc 4x4 f32x4.
// ---------------------------------------------------------------------------
__global__ __launch_bounds__(256) void gemm_fused(
    const float* __restrict__ q_rep, const float* __restrict__ d_rep,
    const int* __restrict__ q_ids, const int* __restrict__ d_ids,
    const int* __restrict__ d_tfs,
    float* __restrict__ S, float* __restrict__ ws_etdf)
{
    // [buf][A=0|B=1][row][colf] f32, linear (NO padding - gll requirement).
    __shared__ __align__(16) float Ls[2][2][128][32];   // 64 KB
    __shared__ float mq_s[128];     // q null mask
    __shared__ float md_s[128];     // d null mask
    __shared__ float mdtf_s[128];   // md * tf
    __shared__ float tf_s[128];     // raw tf (em term is unmasked)
    __shared__ int4  qk_s[128];     // q id keys
    __shared__ int4  dk_s[128];     // d id keys

    const int tid  = threadIdx.x;
    const int wave = tid >> 6;
    const int lane = tid & 63;
    const int bid  = blockIdx.x;
    const int b    = bid & 63;
    const int t    = bid >> 6;          // tile 0..3
    const int m0   = (t & 1) * 128;
    const int n0   = (t >> 1) * 128;

    // Masks / keys / tf into LDS (covered by the prologue __syncthreads).
    if (tid < 128) {
        int4 qa = *(const int4*)(q_ids + ((size_t)b * NW_ + m0 + tid) * 4);
        qk_s[tid] = qa;
        mq_s[tid] = (qa.x == 0 && qa.y == 0 && qa.z == 0 && qa.w == 0) ? 0.f : 1.f;
    } else {
        const int r = tid - 128;
        int4 da = *(const int4*)(d_ids + ((size_t)b * NW_ + n0 + r) * 4);
        dk_s[r] = da;
        float md = (da.x == 0 && da.y == 0 && da.z == 0 && da.w == 0) ? 0.f : 1.f;
        float tf = (float)d_tfs[(size_t)b * NW_ + n0 + r];
        md_s[r]   = md;
        tf_s[r]   = tf;
        mdtf_s[r] = md * tf;
    }

    // Staging map. Lane covers row srow8 = lane>>3 (within an 8-row group),
    // stored 16B slot = lane&7. The slot holds GLOBAL segment
    // gseg = (lane&7)^(lane>>3)  [= slot ^ (row&7)] - the rule-#21 pair of
    // the read-side XOR below. LDS dest per gll instr is wave-uniform; HW
    // adds lane*16, matching (lane>>3)*128 + (lane&7)*16 = lane*16.
    const int srow8 = lane >> 3;
    const int gseg  = (lane & 7) ^ srow8;
    const float* Abase = q_rep + ((size_t)b * NW_ + m0) * H_;
    const float* Bbase = d_rep + ((size_t)b * NW_ + n0) * H_;

    auto stage = [&](int buf, int kc) {
#pragma unroll
        for (int i = 0; i < 4; ++i) {
            const int rbase = i * 32 + wave * 8;        // wave-uniform
            const int row   = rbase + srow8;            // per-lane
            GLL16(Abase + (size_t)row * H_ + kc * 32 + gseg * 4,
                  &Ls[buf][0][rbase][0]);
            GLL16(Bbase + (size_t)row * H_ + kc * 32 + gseg * 4,
                  &Ls[buf][1][rbase][0]);
        }
    };

    f32x4 acc[4][4];
#pragma unroll
    for (int i = 0; i < 4; ++i)
#pragma unroll
        for (int j = 0; j < 4; ++j)
            acc[i][j] = (f32x4){0.f, 0.f, 0.f, 0.f};

    const int fr  = lane & 15;
    const int fj0 = (lane >> 4) * 2;    // 16B seg of the 8-float k-slice
    const int qm  = wave >> 1;          // quadrant row (64-row strip)
    const int qn  = wave & 1;           // quadrant col (64-col strip)

    // Fragment read: floats [g*8, g*8+8) of row R = two b128 at swizzled
    // slots (fj0^ (R&7)), (fj0+1 ^ (R&7)); cvt f32->bf16 in-register.
    auto rdfrag = [&](int buf, int mat, int R) -> bf16x8 {
        const char* rowp = (const char*)&Ls[buf][mat][R][0];
        const int c = R & 7;
        float4 v0 = *(const float4*)(rowp + ((fj0 ^ c) * 16));
        float4 v1 = *(const float4*)(rowp + (((fj0 + 1) ^ c) * 16));
        return (bf16x8){ (__bf16)v0.x, (__bf16)v0.y, (__bf16)v0.z, (__bf16)v0.w,
                         (__bf16)v1.x, (__bf16)v1.y, (__bf16)v1.z, (__bf16)v1.w };
    };

    // Prologue: stage chunk 0; barrier also publishes masks/keys.
    stage(0, 0);
    __syncthreads();

#pragma unroll
    for (int kc = 0; kc < 24; ++kc) {
        const int buf = kc & 1;
        if (kc < 23) stage(buf ^ 1, kc + 1);   // async, in flight over compute
        bf16x8 af[4], bfr[4];
#pragma unroll
        for (int i = 0; i < 4; ++i)
            af[i] = rdfrag(buf, 0, qm * 64 + i * 16 + fr);
#pragma unroll
        for (int j = 0; j < 4; ++j)
            bfr[j] = rdfrag(buf, 1, qn * 64 + j * 16 + fr);
#pragma unroll
        for (int i = 0; i < 4; ++i)
#pragma unroll
            for (int j = 0; j < 4; ++j)
                acc[i][j] = __builtin_amdgcn_mfma_f32_16x16x32_bf16(
                    af[i], bfr[j], acc[i][j], 0, 0, 0);
        __syncthreads();   // vmcnt+lgkm drain: next buf fully staged
    }

    // Epilogue. C layout: col = lane&15, row = (lane>>4)*4 + reg.
    // etdf contribution per (row, col): AB*mq*md*v*tf + 0.9*em*tf.
    const int cn = lane & 15;
    const int qg = lane >> 4;
    float md_l[4], mdtf_l[4], tf_l[4];
    int4  dk_l[4];
#pragma unroll
    for (int j = 0; j < 4; ++j) {
        const int c = qn * 64 + j * 16 + cn;
        md_l[j]   = md_s[c];
        mdtf_l[j] = mdtf_s[c];
        tf_l[j]   = tf_s[c];
        dk_l[j]   = dk_s[c];
    }
    float* Sbase = S + ((size_t)b * NW_ + m0 + qm * 64) * NW_ + n0 + qn * 64;

    float rs[16];
#pragma unroll
    for (int i = 0; i < 4; ++i)
#pragma unroll
        for (int r = 0; r < 4; ++r) {
            const int row = i * 16 + qg * 4 + r;
            const float mq = mq_s[qm * 64 + row];
            const int4  qk = qk_s[qm * 64 + row];
            float sdot = 0.f, sem = 0.f;
#pragma unroll
            for (int j = 0; j < 4; ++j) {
                const float v = acc[i][j][r];
                Sbase[(size_t)row * NW_ + j * 16 + cn] = v * mq * md_l[j];
                sdot += v * mdtf_l[j];
                const int4 dk = dk_l[j];
                if (dk.x == qk.x && dk.y == qk.y && dk.z == qk.z && dk.w == qk.w)
                    sem += tf_l[j];
            }
            rs[i * 4 + r] = mq * AB_ * sdot + OMB_ * sem;
        }
    // Reduce over the 16 lanes of each quad-group (rows identical there).
#pragma unroll
    for (int off = 1; off <= 8; off <<= 1)
#pragma unroll
        for (int e = 0; e < 16; ++e)
            rs[e] += __shfl_xor(rs[e], off);
    if (cn == 0) {
#pragma unroll
        for (int i = 0; i < 4; ++i)
#pragma unroll
            for (int r = 0; r < 4; ++r)
                atomicAdd(&ws_etdf[(size_t)b * NW_ + m0 + qm * 64 + i * 16 + qg * 4 + r],
                          rs[i * 4 + r]);
    }
}

// ---------------------------------------------------------------------------
// Final: per batch, dl = sum(tf); dtw = 1.1*etdf/(etdf + K1*(1-Bp+Bp*dl/AVDL)
// + 1e-8); s[b] = sum_q qtw*dtw.  One wave per batch.
// ---------------------------------------------------------------------------
__global__ __launch_bounds__(64) void final_kernel(
    const float* __restrict__ ws_etdf, const int* __restrict__ d_tfs,
    const float* __restrict__ qtw, float* __restrict__ out)
{
    const int b = blockIdx.x;
    const int lane = threadIdx.x;

    float4 ev = *(const float4*)(ws_etdf + (size_t)b * NW_ + lane * 4);
    int4  tf4 = *(const int4*)(d_tfs   + (size_t)b * NW_ + lane * 4);
    float4 qv = *(const float4*)(qtw    + (size_t)b * NW_ + lane * 4);

    float dl = (float)(tf4.x + tf4.y + tf4.z + tf4.w);
#pragma unroll
    for (int off = 32; off; off >>= 1) dl += __shfl_xor(dl, off);

    const float c = K1_ * (1.f - BP_ + BP_ * dl / AVDL_);
    float ew[4] = {ev.x, ev.y, ev.z, ev.w};
    float qw[4] = {qv.x, qv.y, qv.z, qv.w};
    float s = 0.f;
#pragma unroll
    for (int j = 0; j < 4; ++j)
        s += qw[j] * (ew[j] * (1.f + K1_)) / (ew[j] + c + 1e-8f);
#pragma unroll
    for (int off = 32; off; off >>= 1) s += __shfl_xor(s, off);
    if (lane == 0) out[b] = s;
}

extern "C" void kernel_launch(void* const* d_in, const int* in_sizes, int n_in,
                              void* d_out, int out_size, void* d_ws, size_t ws_size,
                              hipStream_t stream)
{
    const float* q_rep = (const float*)d_in[0];
    const float* d_rep = (const float*)d_in[1];
    const float* qtw   = (const float*)d_in[2];
    const int*   q_ids = (const int*)d_in[3];
    const int*   d_ids = (const int*)d_in[4];
    const int*   d_tfs = (const int*)d_in[5];

    float* out = (float*)d_out;
    float* S   = out + B_;              // d_expanded_tf, [B, NW, NW]
    float* ws_etdf = (float*)d_ws;      // [B, NW] f32

    hipMemsetAsync(ws_etdf, 0, (size_t)B_ * NW_ * sizeof(float), stream);

    gemm_fused<<<256, 256, 0, stream>>>(q_rep, d_rep, q_ids, d_ids, d_tfs,
                                        S, ws_etdf);
    final_kernel<<<B_, 64, 0, stream>>>(ws_etdf, d_tfs, qtw, out);
}

// Round 7
// 157.259 us; speedup vs baseline: 1.0174x; 1.0174x over previous
//
#include <hip/hip_runtime.h>
#include <hip/hip_bf16.h>

#define B_   64
#define NW_  256
#define H_   768

#define AB_    (0.1f / 768.0f)   // ALPHA*BETA
#define OMB_   0.9f              // 1 - BETA
#define K1_    0.1f
#define BP_    1.2f
#define AVDL_  50.0f

typedef __bf16 bf16x8 __attribute__((ext_vector_type(8)));
typedef float  f32x4  __attribute__((ext_vector_type(4)));

// Async global->LDS, 16B per lane, no VGPR round-trip (learn_hip CM#1).
// LDS dest is wave-uniform base + lane*16; global src is per-lane.
#define GLL16(g, l)                                                        \
    __builtin_amdgcn_global_load_lds(                                      \
        (const __attribute__((address_space(1))) void*)(g),                \
        (__attribute__((address_space(3))) void*)(l), 16, 0, 0)

// Counted-vmcnt barrier (T4): wait until <=N vector-memory ops outstanding,
// then barrier. NEVER 0 in the main loop - prefetch loads stay in flight
// across the barrier (AITER/m201 pattern; isolated +38-73% in m218).
#define WAIT_VM_BAR(n) \
    asm volatile("s_waitcnt vmcnt(" #n ")\n\ts_barrier" ::: "memory")

// Close the read phase: LDS reads retired, then barrier (no vmcnt drain).
#define BAR_LGKM() asm volatile("s_waitcnt lgkmcnt(0)\n\ts_barrier" ::: "memory")

// ---------------------------------------------------------------------------
// m97-structure GEMM: 128x128 tile, BK=32, double-buffered LDS staged via
// global_load_lds, COUNTED-vmcnt schedule, fused score epilogue.
// R6 post-mortem: gll staging + per-chunk __syncthreads = 57us, WORSE than
// R0's 44. Cause: __syncthreads drains vmcnt(0), so each chunk's 8 async
// loads eat full L2-miss latency (~600+cyc; 12MB/XCD working set thrashes
// the 4MB L2) serially inside the chunk, with 1 block/CU to cover it.
// That is the documented m97 barrier-drain stall. R7 changes ONLY the sync
// schedule to the proven fix (T4, +38-73% isolated): per iter,
//   stage(kc+1) -> buf^1            (8 gll; prev iter's closing barrier
//                                    already separated that buffer's readers)
//   s_waitcnt vmcnt(8); s_barrier   (stage(kc) landed; stage(kc+1) still
//                                    IN FLIGHT across the barrier)
//   ds_read frags + MFMA            (consume buf[kc&1])
//   s_waitcnt lgkmcnt(0); s_barrier (close reads; no vmcnt drain)
// Each stage now has a full iteration (MFMA + 2 barriers) to land instead
// of zero. Hazards: WAR via closing barrier, RAW via vmcnt(8)+barrier,
// WAW via buffer alternation.
// Grid 256 = 4 tiles x 64 batches, bid=t*64+b -> XCD=b%8: one batch's
// tiles share an XCD L2. Wave w: 64x64 quadrant (qm=w>>1, qn=w&1).
// ---------------------------------------------------------------------------
__global__ __launch_bounds__(256) void gemm_fused(
    const float* __restrict__ q_rep, const float* __restrict__ d_rep,
    const int* __restrict__ q_ids, const int* __restrict__ d_ids,
    const int* __restrict__ d_tfs,
    float* __restrict__ S, float* __restrict__ ws_etdf)
{
    // [buf][A=0|B=1][row][colf] f32, linear (NO padding - gll requirement).
    __shared__ __align__(16) float Ls[2][2][128][32];   // 64 KB
    __shared__ float mq_s[128];     // q null mask
    __shared__ float md_s[128];     // d null mask
    __shared__ float mdtf_s[128];   // md * tf
    __shared__ float tf_s[128];     // raw tf (em term is unmasked)
    __shared__ int4  qk_s[128];     // q id keys
    __shared__ int4  dk_s[128];     // d id keys

    const int tid  = threadIdx.x;
    const int wave = tid >> 6;
    const int lane = tid & 63;
    const int bid  = blockIdx.x;
    const int b    = bid & 63;
    const int t    = bid >> 6;          // tile 0..3
    const int m0   = (t & 1) * 128;
    const int n0   = (t >> 1) * 128;

    // Masks / keys / tf into LDS (covered by the prologue __syncthreads).
    if (tid < 128) {
        int4 qa = *(const int4*)(q_ids + ((size_t)b * NW_ + m0 + tid) * 4);
        qk_s[tid] = qa;
        mq_s[tid] = (qa.x == 0 && qa.y == 0 && qa.z == 0 && qa.w == 0) ? 0.f : 1.f;
    } else {
        const int r = tid - 128;
        int4 da = *(const int4*)(d_ids + ((size_t)b * NW_ + n0 + r) * 4);
        dk_s[r] = da;
        float md = (da.x == 0 && da.y == 0 && da.z == 0 && da.w == 0) ? 0.f : 1.f;
        float tf = (float)d_tfs[(size_t)b * NW_ + n0 + r];
        md_s[r]   = md;
        tf_s[r]   = tf;
        mdtf_s[r] = md * tf;
    }

    // Staging map. Lane covers row srow8 = lane>>3 (within an 8-row group),
    // stored 16B slot = lane&7. The slot holds GLOBAL segment
    // gseg = (lane&7)^(lane>>3) [= slot ^ (row&7)] - the rule-#21 pair of
    // the read-side XOR below. LDS dest per gll instr is wave-uniform; HW
    // adds lane*16, matching (lane>>3)*128 + (lane&7)*16 = lane*16.
    const int srow8 = lane >> 3;
    const int gseg  = (lane & 7) ^ srow8;
    const float* Abase = q_rep + ((size_t)b * NW_ + m0) * H_;
    const float* Bbase = d_rep + ((size_t)b * NW_ + n0) * H_;

    auto stage = [&](int buf, int kc) {
#pragma unroll
        for (int i = 0; i < 4; ++i) {
            const int rbase = i * 32 + wave * 8;        // wave-uniform
            const int row   = rbase + srow8;            // per-lane
            GLL16(Abase + (size_t)row * H_ + kc * 32 + gseg * 4,
                  &Ls[buf][0][rbase][0]);
            GLL16(Bbase + (size_t)row * H_ + kc * 32 + gseg * 4,
                  &Ls[buf][1][rbase][0]);
        }
    };

    f32x4 acc[4][4];
#pragma unroll
    for (int i = 0; i < 4; ++i)
#pragma unroll
        for (int j = 0; j < 4; ++j)
            acc[i][j] = (f32x4){0.f, 0.f, 0.f, 0.f};

    const int fr  = lane & 15;
    const int fj0 = (lane >> 4) * 2;    // 16B seg of the 8-float k-slice
    const int qm  = wave >> 1;          // quadrant row (64-row strip)
    const int qn  = wave & 1;           // quadrant col (64-col strip)

    // Fragment read: floats [g*8, g*8+8) of row R = two b128 at swizzled
    // slots (fj0 ^ (R&7)), ((fj0+1) ^ (R&7)); cvt f32->bf16 in-register.
    // Slot distribution across a wave is uniform (8 lanes/slot) -> b128
    // read runs at its 8-bank-round floor.
    auto rdfrag = [&](int buf, int mat, int R) -> bf16x8 {
        const char* rowp = (const char*)&Ls[buf][mat][R][0];
        const int c = R & 7;
        float4 v0 = *(const float4*)(rowp + ((fj0 ^ c) * 16));
        float4 v1 = *(const float4*)(rowp + (((fj0 + 1) ^ c) * 16));
        return (bf16x8){ (__bf16)v0.x, (__bf16)v0.y, (__bf16)v0.z, (__bf16)v0.w,
                         (__bf16)v1.x, (__bf16)v1.y, (__bf16)v1.z, (__bf16)v1.w };
    };

    // Prologue: stage chunk 0; full drain once (entry state: vmcnt=0,
    // buf0 landed, masks visible).
    stage(0, 0);
    __syncthreads();

#pragma unroll
    for (int kc = 0; kc < 24; ++kc) {
        const int buf = kc & 1;
        if (kc < 23) {
            stage(buf ^ 1, kc + 1);     // 8 gll into buf^1, async
            WAIT_VM_BAR(8);             // stage(kc) landed; kc+1 in flight
        } else {
            WAIT_VM_BAR(0);             // last chunk: nothing in flight
        }
        bf16x8 af[4], bfr[4];
#pragma unroll
        for (int i = 0; i < 4; ++i)
            af[i] = rdfrag(buf, 0, qm * 64 + i * 16 + fr);
#pragma unroll
        for (int j = 0; j < 4; ++j)
            bfr[j] = rdfrag(buf, 1, qn * 64 + j * 16 + fr);
#pragma unroll
        for (int i = 0; i < 4; ++i)
#pragma unroll
            for (int j = 0; j < 4; ++j)
                acc[i][j] = __builtin_amdgcn_mfma_f32_16x16x32_bf16(
                    af[i], bfr[j], acc[i][j], 0, 0, 0);
        BAR_LGKM();                     // close reads; NO vmcnt drain
    }

    // Epilogue. C layout: col = lane&15, row = (lane>>4)*4 + reg.
    // etdf contribution per (row, col): AB*mq*md*v*tf + 0.9*em*tf.
    const int cn = lane & 15;
    const int qg = lane >> 4;
    float md_l[4], mdtf_l[4], tf_l[4];
    int4  dk_l[4];
#pragma unroll
    for (int j = 0; j < 4; ++j) {
        const int c = qn * 64 + j * 16 + cn;
        md_l[j]   = md_s[c];
        mdtf_l[j] = mdtf_s[c];
        tf_l[j]   = tf_s[c];
        dk_l[j]   = dk_s[c];
    }
    float* Sbase = S + ((size_t)b * NW_ + m0 + qm * 64) * NW_ + n0 + qn * 64;

    float rs[16];
#pragma unroll
    for (int i = 0; i < 4; ++i)
#pragma unroll
        for (int r = 0; r < 4; ++r) {
            const int row = i * 16 + qg * 4 + r;
            const float mq = mq_s[qm * 64 + row];
            const int4  qk = qk_s[qm * 64 + row];
            float sdot = 0.f, sem = 0.f;
#pragma unroll
            for (int j = 0; j < 4; ++j) {
                const float v = acc[i][j][r];
                Sbase[(size_t)row * NW_ + j * 16 + cn] = v * mq * md_l[j];
                sdot += v * mdtf_l[j];
                const int4 dk = dk_l[j];
                if (dk.x == qk.x && dk.y == qk.y && dk.z == qk.z && dk.w == qk.w)
                    sem += tf_l[j];
            }
            rs[i * 4 + r] = mq * AB_ * sdot + OMB_ * sem;
        }
    // Reduce over the 16 lanes of each quad-group (rows identical there).
#pragma unroll
    for (int off = 1; off <= 8; off <<= 1)
#pragma unroll
        for (int e = 0; e < 16; ++e)
            rs[e] += __shfl_xor(rs[e], off);
    if (cn == 0) {
#pragma unroll
        for (int i = 0; i < 4; ++i)
#pragma unroll
            for (int r = 0; r < 4; ++r)
                atomicAdd(&ws_etdf[(size_t)b * NW_ + m0 + qm * 64 + i * 16 + qg * 4 + r],
                          rs[i * 4 + r]);
    }
}

// ---------------------------------------------------------------------------
// Final: per batch, dl = sum(tf); dtw = 1.1*etdf/(etdf + K1*(1-Bp+Bp*dl/AVDL)
// + 1e-8); s[b] = sum_q qtw*dtw.  One wave per batch.
// ---------------------------------------------------------------------------
__global__ __launch_bounds__(64) void final_kernel(
    const float* __restrict__ ws_etdf, const int* __restrict__ d_tfs,
    const float* __restrict__ qtw, float* __restrict__ out)
{
    const int b = blockIdx.x;
    const int lane = threadIdx.x;

    float4 ev = *(const float4*)(ws_etdf + (size_t)b * NW_ + lane * 4);
    int4  tf4 = *(const int4*)(d_tfs   + (size_t)b * NW_ + lane * 4);
    float4 qv = *(const float4*)(qtw    + (size_t)b * NW_ + lane * 4);

    float dl = (float)(tf4.x + tf4.y + tf4.z + tf4.w);
#pragma unroll
    for (int off = 32; off; off >>= 1) dl += __shfl_xor(dl, off);

    const float c = K1_ * (1.f - BP_ + BP_ * dl / AVDL_);
    float ew[4] = {ev.x, ev.y, ev.z, ev.w};
    float qw[4] = {qv.x, qv.y, qv.z, qv.w};
    float s = 0.f;
#pragma unroll
    for (int j = 0; j < 4; ++j)
        s += qw[j] * (ew[j] * (1.f + K1_)) / (ew[j] + c + 1e-8f);
#pragma unroll
    for (int off = 32; off; off >>= 1) s += __shfl_xor(s, off);
    if (lane == 0) out[b] = s;
}

extern "C" void kernel_launch(void* const* d_in, const int* in_sizes, int n_in,
                              void* d_out, int out_size, void* d_ws, size_t ws_size,
                              hipStream_t stream)
{
    const float* q_rep = (const float*)d_in[0];
    const float* d_rep = (const float*)d_in[1];
    const float* qtw   = (const float*)d_in[2];
    const int*   q_ids = (const int*)d_in[3];
    const int*   d_ids = (const int*)d_in[4];
    const int*   d_tfs = (const int*)d_in[5];

    float* out = (float*)d_out;
    float* S   = out + B_;              // d_expanded_tf, [B, NW, NW]
    float* ws_etdf = (float*)d_ws;      // [B, NW] f32

    hipMemsetAsync(ws_etdf, 0, (size_t)B_ * NW_ * sizeof(float), stream);

    gemm_fused<<<256, 256, 0, stream>>>(q_rep, d_rep, q_ids, d_ids, d_tfs,
                                        S, ws_etdf);
    final_kernel<<<B_, 64, 0, stream>>>(ws_etdf, d_tfs, qtw, out);
}

// Round 9
// 153.155 us; speedup vs baseline: 1.0447x; 1.0268x over previous
//
#include <hip/hip_runtime.h>
#include <hip/hip_bf16.h>

#define B_   64
#define NW_  256
#define H_   768

#define AB_    (0.1f / 768.0f)   // ALPHA*BETA
#define OMB_   0.9f              // 1 - BETA
#define K1_    0.1f
#define BP_    1.2f
#define AVDL_  50.0f

typedef __bf16 bf16x8 __attribute__((ext_vector_type(8)));
typedef float  f32x4  __attribute__((ext_vector_type(4)));

// Async global->LDS, 16B per lane, no VGPR round-trip (learn_hip CM#1).
// LDS dest is wave-uniform base + lane*16; global src is per-lane.
#define GLL16(g, l)                                                        \
    __builtin_amdgcn_global_load_lds(                                      \
        (const __attribute__((address_space(1))) void*)(g),                \
        (__attribute__((address_space(3))) void*)(l), 16, 0, 0)

// Counted-vmcnt barrier (T4): wait until <=N vector-memory ops outstanding,
// then barrier. vmcnt retires IN ORDER, so vmcnt(N) = "wait for all but the
// N newest loads". NEVER 0 in the main loop.
#define WAIT_VM_BAR(n) \
    asm volatile("s_waitcnt vmcnt(" #n ")\n\ts_barrier" ::: "memory")

// Close the read phase: LDS reads retired, then barrier (no vmcnt drain).
#define BAR_LGKM() asm volatile("s_waitcnt lgkmcnt(0)\n\ts_barrier" ::: "memory")

// ---------------------------------------------------------------------------
// m97-structure GEMM: 128x128 tile, BK=32, TRIPLE-buffered LDS staged via
// global_load_lds, counted-vmcnt schedule with PREFETCH DISTANCE 2.
// R8 post-mortem: container failed twice with the 4-buffer/134KB-LDS
// variant - 134KB exceeds every verified precedent (R6: 70KB on this
// harness; HipKittens m201: 128KB). Likely launch-level failure, not infra.
// R9 runs the SAME depth-scaling experiment hedged to 3 buffers / 102KB:
// R6 (zero cover) = 57.4us, R7 (one-iter cover, ~350cyc) = 54.8us; the
// 12.5MB/XCD working set misses the 4MB L2 -> ~500-900cyc L3 service, so
// every iteration still stalls at the vmcnt. Depth-2 gives ~700-800cyc of
// cover: stage(kc+2) issued at iter kc; vmcnt(16) waits exactly for
// stage(kc) (in-order retirement) while stages kc+1,kc+2 (16 loads) stay
// in flight across both barriers. Tail: 16->8->0. Max 24 outstanding/wave.
// Hazards: WAR - stage((kc+2)%3) overwrites the buffer read in iter kc-1,
// whose reads closed at iter kc-1's BAR_LGKM, before the stage issues.
// RAW - per-wave vmcnt confirms its own rows; s_barrier publishes all
// waves'. WAW - 3-way rotation.
// Grid 256 = 4 tiles x 64 batches, bid=t*64+b -> XCD=b%8: one batch's
// tiles share an XCD L2. Wave w: 64x64 quadrant (qm=w>>1, qn=w&1).
// ---------------------------------------------------------------------------
__global__ __launch_bounds__(256) void gemm_fused(
    const float* __restrict__ q_rep, const float* __restrict__ d_rep,
    const int* __restrict__ q_ids, const int* __restrict__ d_ids,
    const int* __restrict__ d_tfs,
    float* __restrict__ S, float* __restrict__ ws_etdf)
{
    // [buf][A=0|B=1][row][colf] f32, linear (NO padding - gll requirement).
    __shared__ __align__(16) float Ls[3][2][128][32];   // 96 KB
    __shared__ float mq_s[128];     // q null mask
    __shared__ float md_s[128];     // d null mask
    __shared__ float mdtf_s[128];   // md * tf
    __shared__ float tf_s[128];     // raw tf (em term is unmasked)
    __shared__ int4  qk_s[128];     // q id keys
    __shared__ int4  dk_s[128];     // d id keys

    const int tid  = threadIdx.x;
    const int wave = tid >> 6;
    const int lane = tid & 63;
    const int bid  = blockIdx.x;
    const int b    = bid & 63;
    const int t    = bid >> 6;          // tile 0..3
    const int m0   = (t & 1) * 128;
    const int n0   = (t >> 1) * 128;

    // Masks / keys / tf into LDS (lgkmcnt(0) in the prologue barrier
    // publishes them).
    if (tid < 128) {
        int4 qa = *(const int4*)(q_ids + ((size_t)b * NW_ + m0 + tid) * 4);
        qk_s[tid] = qa;
        mq_s[tid] = (qa.x == 0 && qa.y == 0 && qa.z == 0 && qa.w == 0) ? 0.f : 1.f;
    } else {
        const int r = tid - 128;
        int4 da = *(const int4*)(d_ids + ((size_t)b * NW_ + n0 + r) * 4);
        dk_s[r] = da;
        float md = (da.x == 0 && da.y == 0 && da.z == 0 && da.w == 0) ? 0.f : 1.f;
        float tf = (float)d_tfs[(size_t)b * NW_ + n0 + r];
        md_s[r]   = md;
        tf_s[r]   = tf;
        mdtf_s[r] = md * tf;
    }

    // Staging map. Lane covers row srow8 = lane>>3 (within an 8-row group),
    // stored 16B slot = lane&7. The slot holds GLOBAL segment
    // gseg = (lane&7)^(lane>>3) [= slot ^ (row&7)] - the rule-#21 pair of
    // the read-side XOR below. LDS dest per gll instr is wave-uniform; HW
    // adds lane*16, matching (lane>>3)*128 + (lane&7)*16 = lane*16.
    const int srow8 = lane >> 3;
    const int gseg  = (lane & 7) ^ srow8;
    const float* Abase = q_rep + ((size_t)b * NW_ + m0) * H_;
    const float* Bbase = d_rep + ((size_t)b * NW_ + n0) * H_;

    auto stage = [&](int buf, int kc) {
#pragma unroll
        for (int i = 0; i < 4; ++i) {
            const int rbase = i * 32 + wave * 8;        // wave-uniform
            const int row   = rbase + srow8;            // per-lane
            GLL16(Abase + (size_t)row * H_ + kc * 32 + gseg * 4,
                  &Ls[buf][0][rbase][0]);
            GLL16(Bbase + (size_t)row * H_ + kc * 32 + gseg * 4,
                  &Ls[buf][1][rbase][0]);
        }
    };

    f32x4 acc[4][4];
#pragma unroll
    for (int i = 0; i < 4; ++i)
#pragma unroll
        for (int j = 0; j < 4; ++j)
            acc[i][j] = (f32x4){0.f, 0.f, 0.f, 0.f};

    const int fr  = lane & 15;
    const int fj0 = (lane >> 4) * 2;    // 16B seg of the 8-float k-slice
    const int qm  = wave >> 1;          // quadrant row (64-row strip)
    const int qn  = wave & 1;           // quadrant col (64-col strip)

    // Fragment read: floats [g*8, g*8+8) of row R = two b128 at swizzled
    // slots (fj0 ^ (R&7)), ((fj0+1) ^ (R&7)); cvt f32->bf16 in-register.
    auto rdfrag = [&](int buf, int mat, int R) -> bf16x8 {
        const char* rowp = (const char*)&Ls[buf][mat][R][0];
        const int c = R & 7;
        float4 v0 = *(const float4*)(rowp + ((fj0 ^ c) * 16));
        float4 v1 = *(const float4*)(rowp + (((fj0 + 1) ^ c) * 16));
        return (bf16x8){ (__bf16)v0.x, (__bf16)v0.y, (__bf16)v0.z, (__bf16)v0.w,
                         (__bf16)v1.x, (__bf16)v1.y, (__bf16)v1.z, (__bf16)v1.w };
    };

    // Prologue: stages 0-1 issued (16 loads in flight); wait only for
    // stage(0) (vmcnt(8)) + mask ds_writes (lgkmcnt(0)), then barrier.
    // Stage 1 stays in flight across it.
    stage(0, 0);
    stage(1, 1);
    asm volatile("s_waitcnt vmcnt(8) lgkmcnt(0)\n\ts_barrier" ::: "memory");

#pragma unroll
    for (int kc = 0; kc < 24; ++kc) {
        const int buf = kc % 3;            // compile-time (full unroll)
        if (kc < 22) {
            stage((kc + 2) % 3, kc + 2);   // 8 gll, 2 iters ahead
            WAIT_VM_BAR(16);               // stage(kc) landed; 16 in flight
        } else if (kc == 22) {
            WAIT_VM_BAR(8);                // stage 23 in flight
        } else {
            WAIT_VM_BAR(0);                // last chunk: drain
        }
        bf16x8 af[4], bfr[4];
#pragma unroll
        for (int i = 0; i < 4; ++i)
            af[i] = rdfrag(buf, 0, qm * 64 + i * 16 + fr);
#pragma unroll
        for (int j = 0; j < 4; ++j)
            bfr[j] = rdfrag(buf, 1, qn * 64 + j * 16 + fr);
#pragma unroll
        for (int i = 0; i < 4; ++i)
#pragma unroll
            for (int j = 0; j < 4; ++j)
                acc[i][j] = __builtin_amdgcn_mfma_f32_16x16x32_bf16(
                    af[i], bfr[j], acc[i][j], 0, 0, 0);
        BAR_LGKM();                        // close reads; NO vmcnt drain
    }

    // Epilogue. C layout: col = lane&15, row = (lane>>4)*4 + reg.
    // etdf contribution per (row, col): AB*mq*md*v*tf + 0.9*em*tf.
    const int cn = lane & 15;
    const int qg = lane >> 4;
    float md_l[4], mdtf_l[4], tf_l[4];
    int4  dk_l[4];
#pragma unroll
    for (int j = 0; j < 4; ++j) {
        const int c = qn * 64 + j * 16 + cn;
        md_l[j]   = md_s[c];
        mdtf_l[j] = mdtf_s[c];
        tf_l[j]   = tf_s[c];
        dk_l[j]   = dk_s[c];
    }
    float* Sbase = S + ((size_t)b * NW_ + m0 + qm * 64) * NW_ + n0 + qn * 64;

    float rs[16];
#pragma unroll
    for (int i = 0; i < 4; ++i)
#pragma unroll
        for (int r = 0; r < 4; ++r) {
            const int row = i * 16 + qg * 4 + r;
            const float mq = mq_s[qm * 64 + row];
            const int4  qk = qk_s[qm * 64 + row];
            float sdot = 0.f, sem = 0.f;
#pragma unroll
            for (int j = 0; j < 4; ++j) {
                const float v = acc[i][j][r];
                Sbase[(size_t)row * NW_ + j * 16 + cn] = v * mq * md_l[j];
                sdot += v * mdtf_l[j];
                const int4 dk = dk_l[j];
                if (dk.x == qk.x && dk.y == qk.y && dk.z == qk.z && dk.w == qk.w)
                    sem += tf_l[j];
            }
            rs[i * 4 + r] = mq * AB_ * sdot + OMB_ * sem;
        }
    // Reduce over the 16 lanes of each quad-group (rows identical there).
#pragma unroll
    for (int off = 1; off <= 8; off <<= 1)
#pragma unroll
        for (int e = 0; e < 16; ++e)
            rs[e] += __shfl_xor(rs[e], off);
    if (cn == 0) {
#pragma unroll
        for (int i = 0; i < 4; ++i)
#pragma unroll
            for (int r = 0; r < 4; ++r)
                atomicAdd(&ws_etdf[(size_t)b * NW_ + m0 + qm * 64 + i * 16 + qg * 4 + r],
                          rs[i * 4 + r]);
    }
}

// ---------------------------------------------------------------------------
// Final: per batch, dl = sum(tf); dtw = 1.1*etdf/(etdf + K1*(1-Bp+Bp*dl/AVDL)
// + 1e-8); s[b] = sum_q qtw*dtw.  One wave per batch.
// ---------------------------------------------------------------------------
__global__ __launch_bounds__(64) void final_kernel(
    const float* __restrict__ ws_etdf, const int* __restrict__ d_tfs,
    const float* __restrict__ qtw, float* __restrict__ out)
{
    const int b = blockIdx.x;
    const int lane = threadIdx.x;

    float4 ev = *(const float4*)(ws_etdf + (size_t)b * NW_ + lane * 4);
    int4  tf4 = *(const int4*)(d_tfs   + (size_t)b * NW_ + lane * 4);
    float4 qv = *(const float4*)(qtw    + (size_t)b * NW_ + lane * 4);

    float dl = (float)(tf4.x + tf4.y + tf4.z + tf4.w);
#pragma unroll
    for (int off = 32; off; off >>= 1) dl += __shfl_xor(dl, off);

    const float c = K1_ * (1.f - BP_ + BP_ * dl / AVDL_);
    float ew[4] = {ev.x, ev.y, ev.z, ev.w};
    float qw[4] = {qv.x, qv.y, qv.z, qv.w};
    float s = 0.f;
#pragma unroll
    for (int j = 0; j < 4; ++j)
        s += qw[j] * (ew[j] * (1.f + K1_)) / (ew[j] + c + 1e-8f);
#pragma unroll
    for (int off = 32; off; off >>= 1) s += __shfl_xor(s, off);
    if (lane == 0) out[b] = s;
}

extern "C" void kernel_launch(void* const* d_in, const int* in_sizes, int n_in,
                              void* d_out, int out_size, void* d_ws, size_t ws_size,
                              hipStream_t stream)
{
    const float* q_rep = (const float*)d_in[0];
    const float* d_rep = (const float*)d_in[1];
    const float* qtw   = (const float*)d_in[2];
    const int*   q_ids = (const int*)d_in[3];
    const int*   d_ids = (const int*)d_in[4];
    const int*   d_tfs = (const int*)d_in[5];

    float* out = (float*)d_out;
    float* S   = out + B_;              // d_expanded_tf, [B, NW, NW]
    float* ws_etdf = (float*)d_ws;      // [B, NW] f32

    hipMemsetAsync(ws_etdf, 0, (size_t)B_ * NW_ * sizeof(float), stream);

    gemm_fused<<<256, 256, 0, stream>>>(q_rep, d_rep, q_ids, d_ids, d_tfs,
                                        S, ws_etdf);
    final_kernel<<<B_, 64, 0, stream>>>(ws_etdf, d_tfs, qtw, out);
}